// Round 3
// baseline (19922.949 us; speedup 1.0000x reference)
//
#include <hip/hip_runtime.h>
#include <math.h>

#define BB 8
#define SMEMN 128
#define DD 512
#define HH 8
#define HDIM 64
#define DFFN 2048
#define NLAYER 3
#define VV 128
#define LLEN 32
#define SOS_T 1
#define EOS_T 2
#define PAD_T 0
#define NB 64

// ---- coherence-point (agent-scope, sc1) accessors: bypass stale L2, no cache inv needed
__device__ __forceinline__ float cload(const float* p) {
    return __hip_atomic_load(p, __ATOMIC_RELAXED, __HIP_MEMORY_SCOPE_AGENT);
}
__device__ __forceinline__ void cstore(float* p, float v) {
    __hip_atomic_store(p, v, __ATOMIC_RELAXED, __HIP_MEMORY_SCOPE_AGENT);
}
__device__ __forceinline__ int icload(const int* p) {
    return __hip_atomic_load(p, __ATOMIC_RELAXED, __HIP_MEMORY_SCOPE_AGENT);
}
__device__ __forceinline__ void icstore(int* p, int v) {
    __hip_atomic_store(p, v, __ATOMIC_RELAXED, __HIP_MEMORY_SCOPE_AGENT);
}

// ---------------------------------------------------------------- init tokens
__global__ __launch_bounds__(512) void init_tokens_kernel(int* __restrict__ tokens) {
    int i = threadIdx.x;
    if (i < BB * (LLEN + 1)) tokens[i] = (i % (LLEN + 1) == 0) ? SOS_T : PAD_T;
}

// ------------------------------------------------- memory @ ca_kv_w (hoisted)
__global__ __launch_bounds__(256) void memkv_kernel(
    const float* __restrict__ mem, const float* __restrict__ Wkv, const float* __restrict__ bkv,
    float* __restrict__ Kmem, float* __restrict__ Vmem)
{
    int l = blockIdx.z;
    const float* Wl = Wkv + (size_t)l * DD * (2 * DD);
    const float* bl = bkv + l * (2 * DD);
    int brow = blockIdx.y * 64, bcol = blockIdx.x * 64;
    __shared__ float As[64][20];
    __shared__ float Bs[16][68];
    int tid = threadIdx.x;
    int ty = tid / 16, tx = tid % 16;
    float acc[4][4] = {};
    for (int k0 = 0; k0 < DD; k0 += 16) {
        {
            int r = tid >> 2, kk = (tid & 3) * 4;
            const float4 av = *(const float4*)(mem + (size_t)(brow + r) * DD + k0 + kk);
            As[r][kk] = av.x; As[r][kk + 1] = av.y; As[r][kk + 2] = av.z; As[r][kk + 3] = av.w;
        }
        {
            int kb = tid >> 4, j = (tid & 15) * 4;
            const float4 bv = *(const float4*)(Wl + (size_t)(k0 + kb) * (2 * DD) + bcol + j);
            Bs[kb][j] = bv.x; Bs[kb][j + 1] = bv.y; Bs[kb][j + 2] = bv.z; Bs[kb][j + 3] = bv.w;
        }
        __syncthreads();
        #pragma unroll
        for (int kk2 = 0; kk2 < 16; kk2++) {
            float a0 = As[ty * 4 + 0][kk2], a1 = As[ty * 4 + 1][kk2];
            float a2 = As[ty * 4 + 2][kk2], a3 = As[ty * 4 + 3][kk2];
            float b0 = Bs[kk2][tx * 4 + 0], b1 = Bs[kk2][tx * 4 + 1];
            float b2 = Bs[kk2][tx * 4 + 2], b3 = Bs[kk2][tx * 4 + 3];
            acc[0][0] += a0 * b0; acc[0][1] += a0 * b1; acc[0][2] += a0 * b2; acc[0][3] += a0 * b3;
            acc[1][0] += a1 * b0; acc[1][1] += a1 * b1; acc[1][2] += a1 * b2; acc[1][3] += a1 * b3;
            acc[2][0] += a2 * b0; acc[2][1] += a2 * b1; acc[2][2] += a2 * b2; acc[2][3] += a2 * b3;
            acc[3][0] += a3 * b0; acc[3][1] += a3 * b1; acc[3][2] += a3 * b2; acc[3][3] += a3 * b3;
        }
        __syncthreads();
    }
    for (int i = 0; i < 4; i++)
        for (int j = 0; j < 4; j++) {
            int row = brow + ty * 4 + i, colg = bcol + tx * 4 + j;
            float v = acc[i][j] + bl[colg];
            if (colg < DD) Kmem[((size_t)l * (BB * SMEMN) + row) * DD + colg] = v;
            else           Vmem[((size_t)l * (BB * SMEMN) + row) * DD + (colg - DD)] = v;
        }
}

// ------------------------------------------- fence-free grid barrier (no L2 inv)
__device__ __forceinline__ void gbar(int* cnt, int target) {
    // __syncthreads drains each wave's vmcnt (sc1 stores reached coherence point)
    asm volatile("s_waitcnt vmcnt(0)" ::: "memory");
    __syncthreads();
    if (threadIdx.x == 0) {
        __hip_atomic_fetch_add(cnt, 1, __ATOMIC_RELAXED, __HIP_MEMORY_SCOPE_AGENT);
        int spins = 0;
        while (__hip_atomic_load(cnt, __ATOMIC_RELAXED, __HIP_MEMORY_SCOPE_AGENT) < target) {
            __builtin_amdgcn_s_sleep(2);
            if (++spins > (1 << 24)) break;  // escape hatch
        }
    }
    __syncthreads();
}

// ------------------------------------------------- coherent stage global->LDS
template <int CNT>
__device__ __forceinline__ void stage_c(float* dst, const float* src, int tid) {
    #pragma unroll
    for (int u = 0; u < CNT; ++u) dst[tid + u * 256] = cload(src + tid + u * 256);
}

// ---------------------------------------------------------------- LN on [8][512] LDS
__device__ __forceinline__ void ln_lds(float* xs, const float* __restrict__ g,
                                       const float* __restrict__ b, int tid,
                                       float* mS, float* rS) {
    int r = tid >> 5, lane = tid & 31;
    float s = 0.f, q = 0.f;
    for (int k = lane; k < DD; k += 32) { float v = xs[r * DD + k]; s += v; q += v * v; }
    for (int off = 16; off; off >>= 1) { s += __shfl_down(s, off, 32); q += __shfl_down(q, off, 32); }
    if (lane == 0) { float m = s / 512.f; mS[r] = m; rS[r] = rsqrtf(q / 512.f - m * m + 1e-5f); }
    __syncthreads();
    for (int i = tid; i < BB * DD; i += 256) {
        int r2 = i >> 9, k = i & 511;
        xs[i] = (xs[i] - mS[r2]) * rS[r2] * g[k] + b[k];
    }
    __syncthreads();
}

// ---------------------------------------------------------------- LN on one 512 row
__device__ __forceinline__ void ln_row(float* x, const float* __restrict__ g,
                                       const float* __restrict__ b_, int tid, float* red) {
    float s = 0.f, q = 0.f;
    for (int k = tid; k < DD; k += 256) { float v = x[k]; s += v; q += v * v; }
    for (int off = 32; off; off >>= 1) { s += __shfl_down(s, off); q += __shfl_down(q, off); }
    if ((tid & 63) == 0) { red[tid >> 6] = s; red[4 + (tid >> 6)] = q; }
    __syncthreads();
    s = red[0] + red[1] + red[2] + red[3];
    q = red[4] + red[5] + red[6] + red[7];
    float m = s / 512.f, ri = rsqrtf(q / 512.f - m * m + 1e-5f);
    for (int k = tid; k < DD; k += 256) x[k] = (x[k] - m) * ri * g[k] + b_[k];
    __syncthreads();
}

// ---------------------------------------------------------------- embed into LDS
__device__ __forceinline__ void embed_ld(float* dst, const float* __restrict__ emb,
                                         const int* tokS, int t, int tid) {
    int pos = (t == 0) ? 0 : (t + 1);
    for (int i = tid; i < BB * DD; i += 256) {
        int r = i >> 9, d = i & 511;
        float freq = expf((float)(d & ~1) * (-9.210340371976184f / 512.f));
        float ang = (float)pos * freq;
        float pev = (d & 1) ? cosf(ang) : sinf(ang);
        dst[i] = emb[(size_t)tokS[r] * DD + d] * 22.62741699796952f + pev;
    }
}

// ---------------------------------------------------------------- GEMV core
// out[8][N] cols [bid*32,bid*32+32) = xs[8][K] @ W[K][N] + bias (+relu) (+resLDS)
template <int K>
__device__ __forceinline__ void gemv_core(
    const float* xs, const float* __restrict__ W,
    const float* __restrict__ bias, int N,
    const float* resLDS, float* out, int relu,
    float* kc, float* vc,
    float* part, int tid, int bid)
{
    const int c = tid & 31, ks = tid >> 5;
    const int col = (bid << 5) + c;
    const int KC = K >> 3;
    const int k0 = ks * KC;
    float acc[8] = {};
    const float* Wp = W + (size_t)k0 * N + col;
    for (int kk = 0; kk < KC; kk += 4) {
        float w0 = Wp[(size_t)(kk + 0) * N];
        float w1 = Wp[(size_t)(kk + 1) * N];
        float w2 = Wp[(size_t)(kk + 2) * N];
        float w3 = Wp[(size_t)(kk + 3) * N];
        #pragma unroll
        for (int r = 0; r < 8; ++r) {
            const float4 xv = *(const float4*)(xs + r * K + k0 + kk);
            acc[r] += xv.x * w0 + xv.y * w1 + xv.z * w2 + xv.w * w3;
        }
    }
    #pragma unroll
    for (int r = 0; r < 8; ++r) part[(ks * 8 + r) * 32 + c] = acc[r];
    __syncthreads();
    {
        int r = tid >> 5, cc = tid & 31;
        int ocol = (bid << 5) + cc;
        float v = 0.f;
        #pragma unroll
        for (int s = 0; s < 8; ++s) v += part[(s * 8 + r) * 32 + cc];
        v += bias[ocol];
        if (relu) v = fmaxf(v, 0.f);
        if (resLDS) v += resLDS[(r << 9) + ocol];
        cstore(out + (size_t)r * N + ocol, v);
        if (kc) {
            if (ocol >= DD) {
                if (ocol < 2 * DD) cstore(kc + (size_t)r * (LLEN * DD) + (ocol - DD), v);
                else               cstore(vc + (size_t)r * (LLEN * DD) + (ocol - 2 * DD), v);
            }
        }
    }
    __syncthreads();
}

// ---------------------------------------------------------------- megakernel
struct MegaParams {
    const float *emb;
    const float *sa_qkv_w, *sa_qkv_b, *sa_out_w, *sa_out_b;
    const float *ca_q_w, *ca_q_b, *ca_out_w, *ca_out_b;
    const float *ln1_g, *ln1_b, *ln2_g, *ln2_b, *ln3_g, *ln3_b;
    const float *ffn_w1, *ffn_b1, *ffn_w2, *ffn_b2, *clf_w, *clf_b;
    int* tokens; int* bar;
    float *Kmem, *Vmem, *Ksa, *Vsa;
    float *qkvb, *attn, *y1, *cat, *y2, *hb, *y3;
    float *out_logits, *out_sampled;
};

__global__ __launch_bounds__(256, 1) void mega_kernel(MegaParams p) {
    __shared__ float xs[BB * DFFN];      // 64 KB staging (max K = 2048)
    __shared__ float rs[BB * DD];        // 16 KB residual / LN scratch
    __shared__ float part[8 * 8 * 32];   // 8 KB gemv partials / scores
    __shared__ float sred[576];          // attention scratch
    __shared__ float mS[8], rS[8], red8[8];
    __shared__ int   tokS[8];
    __shared__ float argv[2];
    __shared__ int   argi[2];
    const int tid = threadIdx.x, bid = blockIdx.x;
    int gen = 0;

    for (int t = 0; t < LLEN; ++t) {
        for (int l = 0; l < NLAYER; ++l) {
            // ---------------- qkv (48 blocks): x = embed | LN3(y3) ----------------
            if (bid < 48) {
                if (l == 0) {
                    if (tid < 8) tokS[tid] = icload(p.tokens + tid * (LLEN + 1) + t);
                    __syncthreads();
                    embed_ld(xs, p.emb, tokS, t, tid);
                    __syncthreads();
                } else {
                    stage_c<16>(xs, p.y3, tid);
                    __syncthreads();
                    ln_lds(xs, p.ln3_g + (l - 1) * DD, p.ln3_b + (l - 1) * DD, tid, mS, rS);
                }
                gemv_core<512>(xs, p.sa_qkv_w + (size_t)l * DD * 3 * DD,
                               p.sa_qkv_b + l * 3 * DD, 3 * DD,
                               nullptr, p.qkvb, 0,
                               p.Ksa + ((size_t)l * (BB * LLEN) + t) * DD,
                               p.Vsa + ((size_t)l * (BB * LLEN) + t) * DD,
                               part, tid, bid);
            }
            gbar(p.bar, (++gen) * NB);

            // ---------------- self-attention (64 blocks, one per (b,h)) ----------------
            {
                const int b = bid >> 3, h = bid & 7;
                if (tid < 64) sred[tid] = cload(p.qkvb + b * (3 * DD) + h * HDIM + tid);
                __syncthreads();
                float* sc = part;
                const int w = tid >> 6, lane = tid & 63;
                // KV rows are write-once then immutable: normal cached loads are safe
                // (a row's lines are never cached by any reader before they're written).
                const float* Kb = p.Ksa + ((size_t)(l * BB + b)) * (LLEN * DD) + h * HDIM;
                for (int j = w; j <= t; j += 4) {
                    float v = sred[lane] * Kb[(size_t)j * DD + lane];
                    for (int off = 32; off; off >>= 1) v += __shfl_down(v, off);
                    if (lane == 0) sc[j] = v * 0.125f;
                }
                __syncthreads();
                if (tid < 64) {
                    float s = (tid <= t) ? sc[tid] : -1e30f;
                    float mx = s;
                    for (int off = 32; off; off >>= 1) mx = fmaxf(mx, __shfl_xor(mx, off));
                    float pe2 = (tid <= t) ? expf(s - mx) : 0.f;
                    float sum = pe2;
                    for (int off = 32; off; off >>= 1) sum += __shfl_xor(sum, off);
                    if (tid <= t) sc[tid] = pe2 / sum;
                }
                __syncthreads();
                {
                    const float* Vb = p.Vsa + ((size_t)(l * BB + b)) * (LLEN * DD) + h * HDIM;
                    float o = 0.f;
                    for (int j = w; j <= t; j += 4) o += sc[j] * Vb[(size_t)j * DD + lane];
                    sred[64 + w * 64 + lane] = o;
                }
                __syncthreads();
                if (tid < 64)
                    cstore(p.attn + b * DD + h * HDIM + tid,
                           sred[64 + tid] + sred[128 + tid] + sred[192 + tid] + sred[256 + tid]);
            }
            gbar(p.bar, (++gen) * NB);

            // ---------------- self-attn out proj + residual x ----------------
            if (bid < 16) {
                stage_c<16>(xs, p.attn, tid);
                if (l == 0) {
                    if (tid < 8) tokS[tid] = icload(p.tokens + tid * (LLEN + 1) + t);
                    __syncthreads();
                    embed_ld(rs, p.emb, tokS, t, tid);
                    __syncthreads();
                } else {
                    stage_c<16>(rs, p.y3, tid);
                    __syncthreads();
                    ln_lds(rs, p.ln3_g + (l - 1) * DD, p.ln3_b + (l - 1) * DD, tid, mS, rS);
                }
                gemv_core<512>(xs, p.sa_out_w + (size_t)l * DD * DD, p.sa_out_b + l * DD, DD,
                               rs, p.y1, 0, nullptr, nullptr, part, tid, bid);
            }
            gbar(p.bar, (++gen) * NB);

            // ---------------- cross-attention, q computed in-block ----------------
            {
                const int b = bid >> 3, h = bid & 7;
                // LN1(y1[b]) in rs[0..511]
                for (int k = tid; k < DD; k += 256) rs[k] = cload(p.y1 + (b << 9) + k);
                __syncthreads();
                ln_row(rs, p.ln1_g + l * DD, p.ln1_b + l * DD, tid, red8);
                // q[64] = rs @ ca_q_w[:, h*64 .. h*64+64)
                {
                    const int c = tid & 63, kk0 = (tid >> 6) * 128;
                    const float* Wp = p.ca_q_w + (size_t)l * DD * DD + (size_t)kk0 * DD + h * HDIM + c;
                    float a = 0.f;
                    #pragma unroll 8
                    for (int k = 0; k < 128; ++k) a += rs[kk0 + k] * Wp[(size_t)k * DD];
                    part[(tid >> 6) * 64 + c] = a;
                }
                __syncthreads();
                if (tid < 64)
                    sred[tid] = part[tid] + part[64 + tid] + part[128 + tid] + part[192 + tid]
                                + p.ca_q_b[l * DD + h * HDIM + tid];
                __syncthreads();
                float* sc = sred + 64;    // 128 scores
                float* po = sred + 192;   // 256 partials
                const int w = tid >> 6, lane = tid & 63;
                const float* Kb = p.Kmem + ((size_t)(l * BB + b)) * (SMEMN * DD) + h * HDIM;
                for (int j = w; j < SMEMN; j += 4) {
                    float v = sred[lane] * Kb[(size_t)j * DD + lane];
                    for (int off = 32; off; off >>= 1) v += __shfl_down(v, off);
                    if (lane == 0) sc[j] = v * 0.125f;
                }
                __syncthreads();
                if (tid < 64) {
                    float s0 = sc[tid], s1 = sc[tid + 64];
                    float mx = fmaxf(s0, s1);
                    for (int off = 32; off; off >>= 1) mx = fmaxf(mx, __shfl_xor(mx, off));
                    float e0 = expf(s0 - mx), e1 = expf(s1 - mx);
                    float sum = e0 + e1;
                    for (int off = 32; off; off >>= 1) sum += __shfl_xor(sum, off);
                    sc[tid] = e0 / sum; sc[tid + 64] = e1 / sum;
                }
                __syncthreads();
                {
                    const float* Vb = p.Vmem + ((size_t)(l * BB + b)) * (SMEMN * DD) + h * HDIM;
                    float o = 0.f;
                    for (int j = w; j < SMEMN; j += 4) o += sc[j] * Vb[(size_t)j * DD + lane];
                    po[w * 64 + lane] = o;
                }
                __syncthreads();
                if (tid < 64)
                    cstore(p.cat + b * DD + h * HDIM + tid,
                           po[tid] + po[64 + tid] + po[128 + tid] + po[192 + tid]);
            }
            gbar(p.bar, (++gen) * NB);

            // ---------------- cross-attn out proj + residual LN1(y1) ----------------
            if (bid < 16) {
                stage_c<16>(xs, p.cat, tid);
                stage_c<16>(rs, p.y1, tid);
                __syncthreads();
                ln_lds(rs, p.ln1_g + l * DD, p.ln1_b + l * DD, tid, mS, rS);
                gemv_core<512>(xs, p.ca_out_w + (size_t)l * DD * DD, p.ca_out_b + l * DD, DD,
                               rs, p.y2, 0, nullptr, nullptr, part, tid, bid);
            }
            gbar(p.bar, (++gen) * NB);

            // ---------------- ffn1 (64 blocks), relu ----------------
            {
                stage_c<16>(xs, p.y2, tid);
                __syncthreads();
                ln_lds(xs, p.ln2_g + l * DD, p.ln2_b + l * DD, tid, mS, rS);
                gemv_core<512>(xs, p.ffn_w1 + (size_t)l * DD * DFFN, p.ffn_b1 + l * DFFN, DFFN,
                               nullptr, p.hb, 1, nullptr, nullptr, part, tid, bid);
            }
            gbar(p.bar, (++gen) * NB);

            // ---------------- ffn2 + residual LN2(y2) ----------------
            if (bid < 16) {
                stage_c<64>(xs, p.hb, tid);
                stage_c<16>(rs, p.y2, tid);
                __syncthreads();
                ln_lds(rs, p.ln2_g + l * DD, p.ln2_b + l * DD, tid, mS, rS);
                gemv_core<2048>(xs, p.ffn_w2 + (size_t)l * DFFN * DD, p.ffn_b2 + l * DD, DD,
                                rs, p.y3, 0, nullptr, nullptr, part, tid, bid);
            }
            gbar(p.bar, (++gen) * NB);
        }
        // ---------------- classifier + argmax (8 blocks) ----------------
        if (bid < 8) {
            for (int k = tid; k < DD; k += 256) xs[k] = cload(p.y3 + (bid << 9) + k);
            __syncthreads();
            float s = 0.f, q = 0.f;
            for (int k = tid; k < DD; k += 256) { float v = xs[k]; s += v; q += v * v; }
            for (int off = 32; off; off >>= 1) { s += __shfl_down(s, off); q += __shfl_down(q, off); }
            if ((tid & 63) == 0) { part[tid >> 6] = s; part[8 + (tid >> 6)] = q; }
            __syncthreads();
            s = part[0] + part[1] + part[2] + part[3];
            q = part[8] + part[9] + part[10] + part[11];
            float m = s / 512.f, ri = rsqrtf(q / 512.f - m * m + 1e-5f);
            const float* g3 = p.ln3_g + 2 * DD;
            const float* b3 = p.ln3_b + 2 * DD;
            for (int k = tid; k < DD; k += 256) xs[DD + k] = (xs[k] - m) * ri * g3[k] + b3[k];
            __syncthreads();
            {
                int cl = tid & 127, kh = tid >> 7;  // K split in 2
                float lg = 0.f;
                const float* Wc = p.clf_w + (size_t)kh * 256 * VV + cl;
                const float* xh = xs + DD + kh * 256;
                #pragma unroll 8
                for (int k = 0; k < 256; ++k) lg += xh[k] * Wc[(size_t)k * VV];
                part[tid] = lg;
            }
            __syncthreads();
            if (tid < 128) {
                float lg = part[tid] + part[128 + tid] + p.clf_b[tid];
                p.out_logits[((size_t)bid * LLEN + t) * VV + tid] = lg;
                float bv = lg; int bi = tid;
                for (int off = 32; off; off >>= 1) {
                    float ov = __shfl_xor(bv, off); int oi = __shfl_xor(bi, off);
                    if (ov > bv || (ov == bv && oi < bi)) { bv = ov; bi = oi; }
                }
                if ((tid & 63) == 0) { argv[tid >> 6] = bv; argi[tid >> 6] = bi; }
            }
            __syncthreads();
            if (tid == 0) {
                int best = (argv[1] > argv[0] || (argv[1] == argv[0] && argi[1] < argi[0]))
                               ? argi[1] : argi[0];
                icstore(p.tokens + bid * (LLEN + 1) + t + 1, best);
            }
        }
        gbar(p.bar, (++gen) * NB);
    }
    // ---------------- finalize sampled ----------------
    if (bid == 0 && tid < BB) {
        int b = tid;
        int toks[LLEN + 1];
        for (int j = 0; j <= LLEN; j++) toks[j] = icload(p.tokens + b * (LLEN + 1) + j);
        int eos = 0;
        for (int j = 1; j <= LLEN; j++) {
            if (toks[j] == EOS_T) { eos = j; break; }
        }
        for (int j = 0; j <= LLEN; j++) {
            int v = toks[j];
            if (eos != 0 && j > eos + 1) v = PAD_T;
            p.out_sampled[b * (LLEN + 1) + j] = (float)v;
        }
    }
}

// --------------------------------------------------------------------- host
extern "C" void kernel_launch(void* const* d_in, const int* in_sizes, int n_in,
                              void* d_out, int out_size, void* d_ws, size_t ws_size,
                              hipStream_t stream) {
    const float* memory   = (const float*)d_in[0];
    const float* emb      = (const float*)d_in[1];
    const float* sa_qkv_w = (const float*)d_in[2];
    const float* sa_qkv_b = (const float*)d_in[3];
    const float* sa_out_w = (const float*)d_in[4];
    const float* sa_out_b = (const float*)d_in[5];
    const float* ca_q_w   = (const float*)d_in[6];
    const float* ca_q_b   = (const float*)d_in[7];
    const float* ca_kv_w  = (const float*)d_in[8];
    const float* ca_kv_b  = (const float*)d_in[9];
    const float* ca_out_w = (const float*)d_in[10];
    const float* ca_out_b = (const float*)d_in[11];
    const float* ln1_g    = (const float*)d_in[12];
    const float* ln1_b    = (const float*)d_in[13];
    const float* ln2_g    = (const float*)d_in[14];
    const float* ln2_b    = (const float*)d_in[15];
    const float* ln3_g    = (const float*)d_in[16];
    const float* ln3_b    = (const float*)d_in[17];
    const float* ffn_w1   = (const float*)d_in[18];
    const float* ffn_b1   = (const float*)d_in[19];
    const float* ffn_w2   = (const float*)d_in[20];
    const float* ffn_b2   = (const float*)d_in[21];
    const float* clf_w    = (const float*)d_in[22];
    const float* clf_b    = (const float*)d_in[23];

    float* f = (float*)d_ws;
    int*   bar    = (int*)d_ws;          // d_ws[0]
    int*   tokens = (int*)d_ws + 64;     // 264 ints
    float* Kmem = f + 512;
    float* Vmem = Kmem + (size_t)NLAYER * BB * SMEMN * DD;
    float* Ksa  = Vmem + (size_t)NLAYER * BB * SMEMN * DD;
    float* Vsa  = Ksa  + (size_t)NLAYER * BB * LLEN * DD;
    float* qkvb = Vsa  + (size_t)NLAYER * BB * LLEN * DD;
    float* attn = qkvb + BB * 3 * DD;
    float* y1   = attn + BB * DD;
    float* cat  = y1   + BB * DD;
    float* y2   = cat  + BB * DD;
    float* hb   = y2   + BB * DD;
    float* y3   = hb   + BB * DFFN;

    float* out_logits  = (float*)d_out;
    float* out_sampled = out_logits + (size_t)BB * LLEN * VV;

    hipMemsetAsync(d_ws, 0, 4096, stream);  // reset barrier counter
    init_tokens_kernel<<<1, 512, 0, stream>>>(tokens);
    {
        dim3 g(16, 16, 3);
        memkv_kernel<<<g, 256, 0, stream>>>(memory, ca_kv_w, ca_kv_b, Kmem, Vmem);
    }

    MegaParams p;
    p.emb = emb;
    p.sa_qkv_w = sa_qkv_w; p.sa_qkv_b = sa_qkv_b;
    p.sa_out_w = sa_out_w; p.sa_out_b = sa_out_b;
    p.ca_q_w = ca_q_w; p.ca_q_b = ca_q_b;
    p.ca_out_w = ca_out_w; p.ca_out_b = ca_out_b;
    p.ln1_g = ln1_g; p.ln1_b = ln1_b;
    p.ln2_g = ln2_g; p.ln2_b = ln2_b;
    p.ln3_g = ln3_g; p.ln3_b = ln3_b;
    p.ffn_w1 = ffn_w1; p.ffn_b1 = ffn_b1;
    p.ffn_w2 = ffn_w2; p.ffn_b2 = ffn_b2;
    p.clf_w = clf_w; p.clf_b = clf_b;
    p.tokens = tokens; p.bar = bar;
    p.Kmem = Kmem; p.Vmem = Vmem; p.Ksa = Ksa; p.Vsa = Vsa;
    p.qkvb = qkvb; p.attn = attn; p.y1 = y1;
    p.cat = cat; p.y2 = y2; p.hb = hb; p.y3 = y3;
    p.out_logits = out_logits; p.out_sampled = out_sampled;

    mega_kernel<<<NB, 256, 0, stream>>>(p);
}

// Round 4
// 8033.463 us; speedup vs baseline: 2.4800x; 2.4800x over previous
//
#include <hip/hip_runtime.h>
#include <hip/hip_fp16.h>
#include <math.h>

#define BB 8
#define SMEMN 128
#define DD 512
#define HDIM 64
#define DFFN 2048
#define NLAYER 3
#define VV 128
#define LLEN 32
#define SOS_T 1
#define EOS_T 2
#define PAD_T 0
#define NB 256

// ---- coherence-point (agent-scope, sc1) accessors
__device__ __forceinline__ float cload(const float* p) {
    return __hip_atomic_load(p, __ATOMIC_RELAXED, __HIP_MEMORY_SCOPE_AGENT);
}
__device__ __forceinline__ float2 cload2(const float* p) {
    unsigned long long u = __hip_atomic_load((const unsigned long long*)p,
                                             __ATOMIC_RELAXED, __HIP_MEMORY_SCOPE_AGENT);
    union { unsigned long long u; float2 f; } c; c.u = u; return c.f;
}
__device__ __forceinline__ void cstore(float* p, float v) {
    __hip_atomic_store(p, v, __ATOMIC_RELAXED, __HIP_MEMORY_SCOPE_AGENT);
}
__device__ __forceinline__ int icload(const int* p) {
    return __hip_atomic_load(p, __ATOMIC_RELAXED, __HIP_MEMORY_SCOPE_AGENT);
}
__device__ __forceinline__ void icstore(int* p, int v) {
    __hip_atomic_store(p, v, __ATOMIC_RELAXED, __HIP_MEMORY_SCOPE_AGENT);
}

// ---------------------------------------------------------------- init tokens
__global__ __launch_bounds__(512) void init_tokens_kernel(int* __restrict__ tokens) {
    int i = threadIdx.x;
    if (i < BB * (LLEN + 1)) tokens[i] = (i % (LLEN + 1) == 0) ? SOS_T : PAD_T;
}

// --------------------------------------------- fp32 [L][K][N] -> fp16 [L][N][K]
__global__ __launch_bounds__(256) void transpose_f16_kernel(
    const float* __restrict__ src, __half* __restrict__ dst, int K, int N)
{
    __shared__ float tile[32][33];
    int l = blockIdx.z;
    int k0 = blockIdx.x * 32, n0 = blockIdx.y * 32;
    const float* s = src + (size_t)l * K * N;
    __half* d = dst + (size_t)l * N * K;
    int r = threadIdx.x >> 5, c = threadIdx.x & 31;
    #pragma unroll
    for (int i = 0; i < 4; i++)
        tile[r + i * 8][c] = s[(size_t)(k0 + r + i * 8) * N + n0 + c];
    __syncthreads();
    #pragma unroll
    for (int i = 0; i < 4; i++)
        d[(size_t)(n0 + r + i * 8) * K + k0 + c] = (__half)tile[c][r + i * 8];
}

// ------------------------------------------------- memory @ ca_kv_w (hoisted)
__global__ __launch_bounds__(256) void memkv_kernel(
    const float* __restrict__ mem, const float* __restrict__ Wkv, const float* __restrict__ bkv,
    float* __restrict__ Kmem, float* __restrict__ Vmem)
{
    int l = blockIdx.z;
    const float* Wl = Wkv + (size_t)l * DD * (2 * DD);
    const float* bl = bkv + l * (2 * DD);
    int brow = blockIdx.y * 64, bcol = blockIdx.x * 64;
    __shared__ float As[64][20];
    __shared__ float Bs[16][68];
    int tid = threadIdx.x;
    int ty = tid / 16, tx = tid % 16;
    float acc[4][4] = {};
    for (int k0 = 0; k0 < DD; k0 += 16) {
        {
            int r = tid >> 2, kk = (tid & 3) * 4;
            const float4 av = *(const float4*)(mem + (size_t)(brow + r) * DD + k0 + kk);
            As[r][kk] = av.x; As[r][kk + 1] = av.y; As[r][kk + 2] = av.z; As[r][kk + 3] = av.w;
        }
        {
            int kb = tid >> 4, j = (tid & 15) * 4;
            const float4 bv = *(const float4*)(Wl + (size_t)(k0 + kb) * (2 * DD) + bcol + j);
            Bs[kb][j] = bv.x; Bs[kb][j + 1] = bv.y; Bs[kb][j + 2] = bv.z; Bs[kb][j + 3] = bv.w;
        }
        __syncthreads();
        #pragma unroll
        for (int kk2 = 0; kk2 < 16; kk2++) {
            float a0 = As[ty * 4 + 0][kk2], a1 = As[ty * 4 + 1][kk2];
            float a2 = As[ty * 4 + 2][kk2], a3 = As[ty * 4 + 3][kk2];
            float b0 = Bs[kk2][tx * 4 + 0], b1 = Bs[kk2][tx * 4 + 1];
            float b2 = Bs[kk2][tx * 4 + 2], b3 = Bs[kk2][tx * 4 + 3];
            acc[0][0] += a0 * b0; acc[0][1] += a0 * b1; acc[0][2] += a0 * b2; acc[0][3] += a0 * b3;
            acc[1][0] += a1 * b0; acc[1][1] += a1 * b1; acc[1][2] += a1 * b2; acc[1][3] += a1 * b3;
            acc[2][0] += a2 * b0; acc[2][1] += a2 * b1; acc[2][2] += a2 * b2; acc[2][3] += a2 * b3;
            acc[3][0] += a3 * b0; acc[3][1] += a3 * b1; acc[3][2] += a3 * b2; acc[3][3] += a3 * b3;
        }
        __syncthreads();
    }
    for (int i = 0; i < 4; i++)
        for (int j = 0; j < 4; j++) {
            int row = brow + ty * 4 + i, colg = bcol + tx * 4 + j;
            float v = acc[i][j] + bl[colg];
            if (colg < DD) Kmem[((size_t)l * (BB * SMEMN) + row) * DD + colg] = v;
            else           Vmem[((size_t)l * (BB * SMEMN) + row) * DD + (colg - DD)] = v;
        }
}

// ------------------------------------------- flag barrier (no RMW serialization)
__device__ __forceinline__ void gbar(int* flags, int* release, int gen, int bid, int tid) {
    asm volatile("s_waitcnt vmcnt(0)" ::: "memory");
    __syncthreads();
    if (bid == 0) {
        if (tid > 0) {
            int spins = 0;
            while (icload(flags + tid * 16) < gen) {
                __builtin_amdgcn_s_sleep(1);
                if (++spins > (1 << 15)) break;  // escape hatch
            }
        }
        __syncthreads();
        if (tid < 8) icstore(release + tid * 16, gen);
    } else {
        if (tid == 0) {
            icstore(flags + bid * 16, gen);
            int spins = 0;
            while (icload(release + (bid & 7) * 16) < gen) {
                __builtin_amdgcn_s_sleep(2);
                if (++spins > (1 << 15)) break;
            }
        }
        __syncthreads();
    }
}

// ------------------------------------------------- staging helpers (coherent)
__device__ __forceinline__ void stage8(float* dst, const float* src, int tid) {
    // 8x512 floats
    for (int i = tid; i < 2048; i += 256) ((float2*)dst)[i] = cload2(src + i * 2);
}
__device__ __forceinline__ void stage_hb_chunk(float* dst, const float* hb, int ch, int tid) {
    for (int i = tid; i < 2048; i += 256) {
        int r = i >> 8, k2 = i & 255;
        ((float2*)dst)[i] = cload2(hb + r * DFFN + ch * 512 + k2 * 2);
    }
}

// ---------------------------------------------------------------- LN on [8][512]
__device__ __forceinline__ void ln_lds(float* xs, const float* __restrict__ g,
                                       const float* __restrict__ b, int tid,
                                       float* mS, float* rS) {
    int r = tid >> 5, lane = tid & 31;
    float s = 0.f, q = 0.f;
    for (int k = lane; k < DD; k += 32) { float v = xs[r * DD + k]; s += v; q += v * v; }
    for (int off = 16; off; off >>= 1) { s += __shfl_down(s, off, 32); q += __shfl_down(q, off, 32); }
    if (lane == 0) { float m = s / 512.f; mS[r] = m; rS[r] = rsqrtf(q / 512.f - m * m + 1e-5f); }
    __syncthreads();
    for (int i = tid; i < BB * DD; i += 256) {
        int r2 = i >> 9, k = i & 511;
        xs[i] = (xs[i] - mS[r2]) * rS[r2] * g[k] + b[k];
    }
    __syncthreads();
}

// ---------------------------------------------------------------- embed into LDS
__device__ __forceinline__ void embed_ld(float* dst, const float* __restrict__ emb,
                                         const int* tokS, int t, int tid) {
    int pos = (t == 0) ? 0 : (t + 1);
    for (int i = tid; i < BB * DD; i += 256) {
        int r = i >> 9, d = i & 511;
        float freq = expf((float)(d & ~1) * (-9.210340371976184f / 512.f));
        float ang = (float)pos * freq;
        float pev = (d & 1) ? cosf(ang) : sinf(ang);
        dst[i] = emb[(size_t)tokS[r] * DD + d] * 22.62741699796952f + pev;
    }
}

// ------------------------------------------------------------ GEMV (LDS weights)
// Accumulate a 512-k chunk: wl = LDS [NCOL][wk_ld] col-major fp16; xsL = LDS [8][512]
template <int NCOL>
__device__ __forceinline__ void gemv_accum512(
    const __half* wl, int wk_ld, int koff, const float* xsL, float acc[8], int tid)
{
    constexpr int NKS = 256 / NCOL;
    constexpr int KPC = 512 / NKS;
    const int c = tid & (NCOL - 1);
    const int ks = tid / NCOL;
    const __half* w = wl + c * wk_ld + koff + ks * KPC;
    const float* x0 = xsL + ks * KPC;
    #pragma unroll
    for (int i4 = 0; i4 < KPC; i4 += 4) {
        float w0 = __half2float(w[i4 + 0]);
        float w1 = __half2float(w[i4 + 1]);
        float w2 = __half2float(w[i4 + 2]);
        float w3 = __half2float(w[i4 + 3]);
        #pragma unroll
        for (int r = 0; r < 8; ++r) {
            const float4 xv = *(const float4*)(x0 + r * 512 + i4);
            acc[r] += xv.x * w0 + xv.y * w1 + xv.z * w2 + xv.w * w3;
        }
    }
}

template <int NCOL>
__device__ __forceinline__ void gemv_finish(
    float acc[8], float* part, int tid, int gcol0,
    const float* __restrict__ bias, const float* resLDS, int relu,
    float* out, int outN,
    float* qb, float* kcb, float* vcb, int kvstride)
{
    #pragma unroll
    for (int r = 0; r < 8; ++r) part[tid * 8 + r] = acc[r];
    __syncthreads();
    constexpr int NKS = 256 / NCOL;
    if (tid < NCOL * 8) {
        int c = tid >> 3, r = tid & 7;
        float v = 0.f;
        for (int ks = 0; ks < NKS; ++ks) v += part[(ks * NCOL + c) * 8 + r];
        int g = gcol0 + c;
        v += bias[g];
        if (relu) v = fmaxf(v, 0.f);
        if (resLDS) v += resLDS[r * 512 + g];
        if (qb) {
            if (g < 512)        cstore(qb + r * 512 + g, v);
            else if (g < 1024)  cstore(kcb + r * kvstride + (g - 512), v);
            else                cstore(vcb + r * kvstride + (g - 1024), v);
        } else {
            cstore(out + (size_t)r * outN + g, v);
        }
    }
    __syncthreads();
}

// ---------------------------------------------------------------- megakernel
struct MegaParams {
    const float *emb;
    const float *sa_qkv_b, *sa_out_b, *ca_q_b, *ca_out_b;
    const float *ln1_g, *ln1_b, *ln2_g, *ln2_b, *ln3_g, *ln3_b;
    const float *ffn_b1, *ffn_b2, *clf_b;
    const __half *qkv16, *saout16, *caq16, *caout16, *ffn116, *ffn216, *clf16;
    int *tokens, *flags, *release;
    float *Kmem, *Vmem, *Ksa, *Vsa;
    float *qbuf, *attnb, *y1, *qca, *cat, *y2, *hb, *y3;
    float *out_logits, *out_sampled;
};

// per-layer LDS weight layout (halfs)
#define LOFF_QKV   0
#define LOFF_SAOUT 4096
#define LOFF_CAQ   5120
#define LOFF_CAOUT 6144
#define LOFF_FFN1  7168
#define LOFF_FFN2  11264
#define LSTRIDE    15360

__device__ __forceinline__ void cp16(__half* dst, const __half* src, int halfs, int tid) {
    const int4* s = (const int4*)src;
    int4* d = (int4*)dst;
    int n = halfs >> 3;
    for (int i = tid; i < n; i += 256) d[i] = s[i];
}

__global__ __launch_bounds__(256, 1) void mega_kernel(MegaParams p) {
    __shared__ __align__(16) __half wlds[3 * LSTRIDE];  // 90 KB
    __shared__ float xs[BB * DD];                        // 16 KB
    __shared__ float rs[BB * DD];                        // 16 KB
    __shared__ float part[2048];                         // 8 KB
    __shared__ float mS[8], rS[8], red8[8];
    __shared__ int   tokS[8];
    __shared__ float argv[2];
    __shared__ int   argi[2];
    const int tid = threadIdx.x, bid = blockIdx.x;
    int gen = 0;

    // ---- one-time LDS weight fill ----
    for (int l = 0; l < NLAYER; ++l) {
        __half* wl = wlds + l * LSTRIDE;
        if (bid < 192)
            cp16(wl + LOFF_QKV, p.qkv16 + ((size_t)l * 1536 + bid * 8) * 512, 4096, tid);
        cp16(wl + LOFF_SAOUT, p.saout16 + ((size_t)l * 512 + bid * 2) * 512, 1024, tid);
        cp16(wl + LOFF_CAQ,   p.caq16   + ((size_t)l * 512 + bid * 2) * 512, 1024, tid);
        cp16(wl + LOFF_CAOUT, p.caout16 + ((size_t)l * 512 + bid * 2) * 512, 1024, tid);
        cp16(wl + LOFF_FFN1,  p.ffn116  + ((size_t)l * 2048 + bid * 8) * 512, 4096, tid);
        cp16(wl + LOFF_FFN2,  p.ffn216  + ((size_t)l * 512 + bid * 2) * 2048, 4096, tid);
    }
    __syncthreads();

    for (int t = 0; t < LLEN; ++t) {
        for (int l = 0; l < NLAYER; ++l) {
            const __half* wl = wlds + l * LSTRIDE;
            // ---------------- P1 qkv (192 blocks, 8 cols each) ----------------
            if (bid < 192) {
                if (l == 0) {
                    if (tid < 8) tokS[tid] = icload(p.tokens + tid * (LLEN + 1) + t);
                    __syncthreads();
                    embed_ld(xs, p.emb, tokS, t, tid);
                    __syncthreads();
                } else {
                    stage8(xs, p.y3, tid);
                    __syncthreads();
                    ln_lds(xs, p.ln3_g + (l - 1) * DD, p.ln3_b + (l - 1) * DD, tid, mS, rS);
                }
                float acc[8] = {};
                gemv_accum512<8>(wl + LOFF_QKV, 512, 0, xs, acc, tid);
                gemv_finish<8>(acc, part, tid, bid * 8, p.sa_qkv_b + l * 1536, nullptr, 0,
                               nullptr, 0, p.qbuf,
                               p.Ksa + ((size_t)l * 256 + t) * 512,
                               p.Vsa + ((size_t)l * 256 + t) * 512, LLEN * DD);
            }
            gbar(p.flags, p.release, ++gen, bid, tid);

            // ---------------- P2 self-attention (64 blocks) ----------------
            if (bid < 64) {
                const int b = bid >> 3, h = bid & 7;
                float* sc  = part;         // 32
                float* qsh = part + 64;    // 64
                float* po  = part + 128;   // 256
                if (tid < 64) qsh[tid] = cload(p.qbuf + b * 512 + h * HDIM + tid);
                __syncthreads();
                const int w = tid >> 6, lane = tid & 63;
                const float* Kb = p.Ksa + ((size_t)(l * 8 + b)) * (LLEN * DD) + h * HDIM;
                for (int j = w; j <= t; j += 4) {
                    float v = qsh[lane] * Kb[(size_t)j * DD + lane];
                    for (int off = 32; off; off >>= 1) v += __shfl_down(v, off);
                    if (lane == 0) sc[j] = v * 0.125f;
                }
                __syncthreads();
                if (tid < 64) {
                    float s = (tid <= t) ? sc[tid] : -1e30f;
                    float mx = s;
                    for (int off = 32; off; off >>= 1) mx = fmaxf(mx, __shfl_xor(mx, off));
                    float pe = (tid <= t) ? expf(s - mx) : 0.f;
                    float sum = pe;
                    for (int off = 32; off; off >>= 1) sum += __shfl_xor(sum, off);
                    if (tid <= t) sc[tid] = pe / sum;
                }
                __syncthreads();
                {
                    const float* Vb = p.Vsa + ((size_t)(l * 8 + b)) * (LLEN * DD) + h * HDIM;
                    float o = 0.f;
                    for (int j = w; j <= t; j += 4) o += sc[j] * Vb[(size_t)j * DD + lane];
                    po[w * 64 + lane] = o;
                }
                __syncthreads();
                if (tid < 64)
                    cstore(p.attnb + b * 512 + h * HDIM + tid,
                           po[tid] + po[64 + tid] + po[128 + tid] + po[192 + tid]);
            }
            gbar(p.flags, p.release, ++gen, bid, tid);

            // ---------------- P3 saout + residual x (256 blocks, 2 cols) ----------------
            {
                stage8(xs, p.attnb, tid);
                if (l == 0) {
                    if (tid < 8) tokS[tid] = icload(p.tokens + tid * (LLEN + 1) + t);
                    __syncthreads();
                    embed_ld(rs, p.emb, tokS, t, tid);
                    __syncthreads();
                } else {
                    stage8(rs, p.y3, tid);
                    __syncthreads();
                    ln_lds(rs, p.ln3_g + (l - 1) * DD, p.ln3_b + (l - 1) * DD, tid, mS, rS);
                }
                float acc[8] = {};
                gemv_accum512<2>(wl + LOFF_SAOUT, 512, 0, xs, acc, tid);
                gemv_finish<2>(acc, part, tid, bid * 2, p.sa_out_b + l * 512, rs, 0,
                               p.y1, 512, nullptr, nullptr, nullptr, 0);
            }
            gbar(p.flags, p.release, ++gen, bid, tid);

            // ---------------- P4 ca_q (256 blocks, 2 cols) ----------------
            {
                stage8(xs, p.y1, tid);
                __syncthreads();
                ln_lds(xs, p.ln1_g + l * DD, p.ln1_b + l * DD, tid, mS, rS);
                float acc[8] = {};
                gemv_accum512<2>(wl + LOFF_CAQ, 512, 0, xs, acc, tid);
                gemv_finish<2>(acc, part, tid, bid * 2, p.ca_q_b + l * 512, nullptr, 0,
                               p.qca, 512, nullptr, nullptr, nullptr, 0);
            }
            gbar(p.flags, p.release, ++gen, bid, tid);

            // ---------------- P5 cross-attention (64 blocks) ----------------
            if (bid < 64) {
                const int b = bid >> 3, h = bid & 7;
                float* qsh = part;         // 64
                float* sc  = part + 64;    // 128
                float* po  = part + 192;   // 128+
                if (tid < 64) qsh[tid] = cload(p.qca + b * 512 + h * HDIM + tid);
                __syncthreads();
                float s = 0.f;
                if (tid < 128) {
                    const float* kp = p.Kmem + (((size_t)(l * 8 + b)) * SMEMN + tid) * DD + h * HDIM;
                    #pragma unroll 8
                    for (int d = 0; d < HDIM; ++d) s += qsh[d] * kp[d];
                    sc[tid] = s * 0.125f;
                }
                __syncthreads();
                if (tid < 64) {
                    float s0 = sc[tid], s1 = sc[tid + 64];
                    float mx = fmaxf(s0, s1);
                    for (int off = 32; off; off >>= 1) mx = fmaxf(mx, __shfl_xor(mx, off));
                    float e0 = expf(s0 - mx), e1 = expf(s1 - mx);
                    float sum = e0 + e1;
                    for (int off = 32; off; off >>= 1) sum += __shfl_xor(sum, off);
                    sc[tid] = e0 / sum; sc[tid + 64] = e1 / sum;
                }
                __syncthreads();
                if (tid < 128) {
                    int d = tid & 63, half = tid >> 6;
                    const float* Vb = p.Vmem + (((size_t)(l * 8 + b)) * SMEMN + half * 64) * DD + h * HDIM + d;
                    float o = 0.f;
                    for (int j = 0; j < 64; ++j) o += sc[half * 64 + j] * Vb[(size_t)j * DD];
                    po[half * 64 + d] = o;
                }
                __syncthreads();
                if (tid < 64)
                    cstore(p.cat + b * 512 + h * HDIM + tid, po[tid] + po[64 + tid]);
            }
            gbar(p.flags, p.release, ++gen, bid, tid);

            // ---------------- P6 caout + residual LN1(y1) ----------------
            {
                stage8(xs, p.cat, tid);
                stage8(rs, p.y1, tid);
                __syncthreads();
                ln_lds(rs, p.ln1_g + l * DD, p.ln1_b + l * DD, tid, mS, rS);
                float acc[8] = {};
                gemv_accum512<2>(wl + LOFF_CAOUT, 512, 0, xs, acc, tid);
                gemv_finish<2>(acc, part, tid, bid * 2, p.ca_out_b + l * 512, rs, 0,
                               p.y2, 512, nullptr, nullptr, nullptr, 0);
            }
            gbar(p.flags, p.release, ++gen, bid, tid);

            // ---------------- P7 ffn1 + relu (256 blocks, 8 cols) ----------------
            {
                stage8(xs, p.y2, tid);
                __syncthreads();
                ln_lds(xs, p.ln2_g + l * DD, p.ln2_b + l * DD, tid, mS, rS);
                float acc[8] = {};
                gemv_accum512<8>(wl + LOFF_FFN1, 512, 0, xs, acc, tid);
                gemv_finish<8>(acc, part, tid, bid * 8, p.ffn_b1 + l * DFFN, nullptr, 1,
                               p.hb, DFFN, nullptr, nullptr, nullptr, 0);
            }
            gbar(p.flags, p.release, ++gen, bid, tid);

            // ---------------- P8 ffn2 + residual LN2(y2) ----------------
            {
                stage8(rs, p.y2, tid);
                __syncthreads();
                ln_lds(rs, p.ln2_g + l * DD, p.ln2_b + l * DD, tid, mS, rS);
                float acc[8] = {};
                #pragma unroll
                for (int ch = 0; ch < 4; ++ch) {
                    __syncthreads();
                    stage_hb_chunk(xs, p.hb, ch, tid);
                    __syncthreads();
                    gemv_accum512<2>(wl + LOFF_FFN2, 2048, ch * 512, xs, acc, tid);
                }
                gemv_finish<2>(acc, part, tid, bid * 2, p.ffn_b2 + l * 512, rs, 0,
                               p.y3, 512, nullptr, nullptr, nullptr, 0);
            }
            gbar(p.flags, p.release, ++gen, bid, tid);
        }
        // ---------------- P9 classifier + argmax (8 blocks) ----------------
        if (bid < 8) {
            const int b = bid;
            float* xn = part;           // 512
            float* p2 = part + 1024;    // 256
            for (int k = tid; k < DD; k += 256) xn[k] = cload(p.y3 + b * DD + k);
            __syncthreads();
            float s = 0.f, q = 0.f;
            for (int k = tid; k < DD; k += 256) { float v = xn[k]; s += v; q += v * v; }
            for (int off = 32; off; off >>= 1) { s += __shfl_down(s, off); q += __shfl_down(q, off); }
            if ((tid & 63) == 0) { red8[tid >> 6] = s; red8[4 + (tid >> 6)] = q; }
            __syncthreads();
            s = red8[0] + red8[1] + red8[2] + red8[3];
            q = red8[4] + red8[5] + red8[6] + red8[7];
            float m = s / 512.f, ri = rsqrtf(q / 512.f - m * m + 1e-5f);
            const float* g3 = p.ln3_g + 2 * DD;
            const float* b3 = p.ln3_b + 2 * DD;
            __syncthreads();
            for (int k = tid; k < DD; k += 256) xn[k] = (xn[k] - m) * ri * g3[k] + b3[k];
            __syncthreads();
            {
                int cl = tid & 127, kh = tid >> 7;
                const __half* Wc = p.clf16 + cl * 512 + kh * 256;
                const float* xh = xn + kh * 256;
                float lg = 0.f;
                #pragma unroll 8
                for (int k = 0; k < 256; ++k) lg += xh[k] * __half2float(Wc[k]);
                p2[tid] = lg;
            }
            __syncthreads();
            if (tid < 128) {
                float lg = p2[tid] + p2[128 + tid] + p.clf_b[tid];
                p.out_logits[((size_t)b * LLEN + t) * VV + tid] = lg;
                float bv = lg; int bi = tid;
                for (int off = 32; off; off >>= 1) {
                    float ov = __shfl_xor(bv, off); int oi = __shfl_xor(bi, off);
                    if (ov > bv || (ov == bv && oi < bi)) { bv = ov; bi = oi; }
                }
                if ((tid & 63) == 0) { argv[tid >> 6] = bv; argi[tid >> 6] = bi; }
            }
            __syncthreads();
            if (tid == 0) {
                int best = (argv[1] > argv[0] || (argv[1] == argv[0] && argi[1] < argi[0]))
                               ? argi[1] : argi[0];
                icstore(p.tokens + b * (LLEN + 1) + t + 1, best);
            }
        }
        gbar(p.flags, p.release, ++gen, bid, tid);
    }
    // ---------------- finalize sampled ----------------
    if (bid == 0 && tid < BB) {
        int b = tid;
        int toks[LLEN + 1];
        for (int j = 0; j <= LLEN; j++) toks[j] = icload(p.tokens + b * (LLEN + 1) + j);
        int eos = 0;
        for (int j = 1; j <= LLEN; j++)
            if (toks[j] == EOS_T) { eos = j; break; }
        for (int j = 0; j <= LLEN; j++) {
            int v = toks[j];
            if (eos != 0 && j > eos + 1) v = PAD_T;
            p.out_sampled[b * (LLEN + 1) + j] = (float)v;
        }
    }
}

// --------------------------------------------------------------------- host
extern "C" void kernel_launch(void* const* d_in, const int* in_sizes, int n_in,
                              void* d_out, int out_size, void* d_ws, size_t ws_size,
                              hipStream_t stream) {
    const float* memory   = (const float*)d_in[0];
    const float* emb      = (const float*)d_in[1];
    const float* sa_qkv_w = (const float*)d_in[2];
    const float* sa_qkv_b = (const float*)d_in[3];
    const float* sa_out_w = (const float*)d_in[4];
    const float* sa_out_b = (const float*)d_in[5];
    const float* ca_q_w   = (const float*)d_in[6];
    const float* ca_q_b   = (const float*)d_in[7];
    const float* ca_kv_w  = (const float*)d_in[8];
    const float* ca_kv_b  = (const float*)d_in[9];
    const float* ca_out_w = (const float*)d_in[10];
    const float* ca_out_b = (const float*)d_in[11];
    const float* ln1_g    = (const float*)d_in[12];
    const float* ln1_b    = (const float*)d_in[13];
    const float* ln2_g    = (const float*)d_in[14];
    const float* ln2_b    = (const float*)d_in[15];
    const float* ln3_g    = (const float*)d_in[16];
    const float* ln3_b    = (const float*)d_in[17];
    const float* ffn_w1   = (const float*)d_in[18];
    const float* ffn_b1   = (const float*)d_in[19];
    const float* ffn_w2   = (const float*)d_in[20];
    const float* ffn_b2   = (const float*)d_in[21];
    const float* clf_w    = (const float*)d_in[22];
    const float* clf_b    = (const float*)d_in[23];

    float* f   = (float*)d_ws;
    int*   wsI = (int*)d_ws;
    int* flags   = wsI;            // 256*16 ints
    int* release = wsI + 4096;     // 8*16 ints
    int* tokens  = wsI + 4352;     // 264 ints
    float* Kmem = f + 8192;
    float* Vmem = Kmem + (size_t)NLAYER * BB * SMEMN * DD;   // 1572864 each
    float* Ksa  = Vmem + (size_t)NLAYER * BB * SMEMN * DD;   // 393216 each
    float* Vsa  = Ksa + (size_t)NLAYER * BB * LLEN * DD;
    float* qbuf = Vsa + (size_t)NLAYER * BB * LLEN * DD;
    float* attnb= qbuf + BB * DD;
    float* y1   = attnb + BB * DD;
    float* qca  = y1 + BB * DD;
    float* cat  = qca + BB * DD;
    float* y2   = cat + BB * DD;
    float* hb   = y2 + BB * DD;
    float* y3   = hb + BB * DFFN;
    __half* qkv16   = (__half*)(y3 + BB * DD);
    __half* saout16 = qkv16 + (size_t)NLAYER * 1536 * 512;
    __half* caq16   = saout16 + (size_t)NLAYER * 512 * 512;
    __half* caout16 = caq16 + (size_t)NLAYER * 512 * 512;
    __half* ffn116  = caout16 + (size_t)NLAYER * 512 * 512;
    __half* ffn216  = ffn116 + (size_t)NLAYER * 2048 * 512;
    __half* clf16   = ffn216 + (size_t)NLAYER * 512 * 2048;

    float* out_logits  = (float*)d_out;
    float* out_sampled = out_logits + (size_t)BB * LLEN * VV;

    hipMemsetAsync(d_ws, 0, 20480, stream);  // flags + release + tokens
    init_tokens_kernel<<<1, 512, 0, stream>>>(tokens);

    transpose_f16_kernel<<<dim3(16, 48, 3), 256, 0, stream>>>(sa_qkv_w, qkv16, 512, 1536);
    transpose_f16_kernel<<<dim3(16, 16, 3), 256, 0, stream>>>(sa_out_w, saout16, 512, 512);
    transpose_f16_kernel<<<dim3(16, 16, 3), 256, 0, stream>>>(ca_q_w,   caq16,   512, 512);
    transpose_f16_kernel<<<dim3(16, 16, 3), 256, 0, stream>>>(ca_out_w, caout16, 512, 512);
    transpose_f16_kernel<<<dim3(16, 64, 3), 256, 0, stream>>>(ffn_w1,   ffn116,  512, 2048);
    transpose_f16_kernel<<<dim3(64, 16, 3), 256, 0, stream>>>(ffn_w2,   ffn216,  2048, 512);
    transpose_f16_kernel<<<dim3(16, 4, 1),  256, 0, stream>>>(clf_w,    clf16,   512, 128);

    {
        dim3 g(16, 16, 3);
        memkv_kernel<<<g, 256, 0, stream>>>(memory, ca_kv_w, ca_kv_b, Kmem, Vmem);
    }

    MegaParams p;
    p.emb = emb;
    p.sa_qkv_b = sa_qkv_b; p.sa_out_b = sa_out_b;
    p.ca_q_b = ca_q_b; p.ca_out_b = ca_out_b;
    p.ln1_g = ln1_g; p.ln1_b = ln1_b;
    p.ln2_g = ln2_g; p.ln2_b = ln2_b;
    p.ln3_g = ln3_g; p.ln3_b = ln3_b;
    p.ffn_b1 = ffn_b1; p.ffn_b2 = ffn_b2; p.clf_b = clf_b;
    p.qkv16 = qkv16; p.saout16 = saout16; p.caq16 = caq16; p.caout16 = caout16;
    p.ffn116 = ffn116; p.ffn216 = ffn216; p.clf16 = clf16;
    p.tokens = tokens; p.flags = flags; p.release = release;
    p.Kmem = Kmem; p.Vmem = Vmem; p.Ksa = Ksa; p.Vsa = Vsa;
    p.qbuf = qbuf; p.attnb = attnb; p.y1 = y1; p.qca = qca;
    p.cat = cat; p.y2 = y2; p.hb = hb; p.y3 = y3;
    p.out_logits = out_logits; p.out_sampled = out_sampled;

    mega_kernel<<<NB, 256, 0, stream>>>(p);
}

// Round 5
// 7310.870 us; speedup vs baseline: 2.7251x; 1.0988x over previous
//
#include <hip/hip_runtime.h>
#include <hip/hip_fp16.h>
#include <math.h>

#define BB 8
#define SMEMN 128
#define DD 512
#define HDIM 64
#define DFFN 2048
#define NLAYER 3
#define VV 128
#define LLEN 32
#define SOS_T 1
#define EOS_T 2
#define PAD_T 0
#define NB 256
#define XP 1028          // xs row pitch (floats)
#define RP 520           // rs row pitch (floats)
#define WLD 520          // weight col pitch (halfs), K=512 mats
#define WLD2 2056        // ffn2 col pitch (halfs), K=2048
#define EMB_SCALE 22.62741699796952f

// LDS weight offsets (halfs)
#define OFF_QKV   0       // 2 layers x 8 cols x 520
#define OFF_SAOUT 8320    // 3 x 2 x 520
#define OFF_CAQ   11440
#define OFF_CAOUT 14560
#define OFF_FFN1  17680   // 3 x 8 x 520
#define OFF_FFN2  30160   // 3 x 2 x 2056
#define WTOT      42496

// ---- agent-scope (sc1) accessors: coherence-point access, no cache inv needed
__device__ __forceinline__ float cload(const float* p) {
    return __hip_atomic_load(p, __ATOMIC_RELAXED, __HIP_MEMORY_SCOPE_AGENT);
}
__device__ __forceinline__ float2 cload2(const float* p) {
    unsigned long long u = __hip_atomic_load((const unsigned long long*)p,
                                             __ATOMIC_RELAXED, __HIP_MEMORY_SCOPE_AGENT);
    union { unsigned long long u; float2 f; } c; c.u = u; return c.f;
}
__device__ __forceinline__ void cstore(float* p, float v) {
    __hip_atomic_store(p, v, __ATOMIC_RELAXED, __HIP_MEMORY_SCOPE_AGENT);
}
__device__ __forceinline__ int icload(const int* p) {
    return __hip_atomic_load(p, __ATOMIC_RELAXED, __HIP_MEMORY_SCOPE_AGENT);
}
__device__ __forceinline__ void icstore(int* p, int v) {
    __hip_atomic_store(p, v, __ATOMIC_RELAXED, __HIP_MEMORY_SCOPE_AGENT);
}

// ---------------------------------------------------------------- prologue
__global__ __launch_bounds__(512) void k_init(int* __restrict__ tokens, float* __restrict__ peR) {
    int i = threadIdx.x;
    if (i < BB * (LLEN + 1)) tokens[i] = (i % (LLEN + 1) == 0) ? SOS_T : PAD_T;
    for (int idx = i; idx < LLEN * DD; idx += 512) {
        int t = idx >> 9, d = idx & 511;
        int pos = (t == 0) ? 0 : (t + 1);
        float freq = expf((float)(d & ~1) * (-9.210340371976184f / 512.f));
        float ang = (float)pos * freq;
        peR[idx] = (d & 1) ? cosf(ang) : sinf(ang);
    }
}

// fp32 [L][K][N] (optionally row-scaled by g[L][K]) -> fp16 [L][N][KPAD]
__global__ __launch_bounds__(256) void t16pad(
    const float* __restrict__ src, const float* __restrict__ g,
    __half* __restrict__ dst, int K, int N, int KPAD)
{
    __shared__ float tile[32][33];
    int z = blockIdx.z;
    int k0 = blockIdx.x * 32, n0 = blockIdx.y * 32;
    const float* s = src + (size_t)z * K * N;
    __half* d = dst + (size_t)z * N * KPAD;
    int r = threadIdx.x >> 5, c = threadIdx.x & 31;
    #pragma unroll
    for (int i = 0; i < 4; i++) {
        int kk = k0 + r + i * 8;
        float gv = g ? g[(size_t)z * K + kk] : 1.f;
        tile[r + i * 8][c] = s[(size_t)kk * N + n0 + c] * gv;
    }
    __syncthreads();
    #pragma unroll
    for (int i = 0; i < 4; i++)
        d[(size_t)(n0 + r + i * 8) * KPAD + k0 + c] = (__half)tile[c][r + i * 8];
}

// SGW[c] = sum_k g[k] W[k][c]; BW[c] = sum_k b[k] W[k][c] + bias[c]  (fp32 exact)
__global__ __launch_bounds__(256) void k_colvec(
    const float* __restrict__ W, const float* __restrict__ g, const float* __restrict__ b,
    const float* __restrict__ bias, float* __restrict__ SGW, float* __restrict__ BW,
    int K, int N)
{
    int z = blockIdx.y;
    int c = blockIdx.x * 256 + threadIdx.x;
    if (c >= N) return;
    const float* Wz = W + (size_t)z * K * N;
    float sg = 0.f, bw = 0.f;
    for (int k = 0; k < K; ++k) {
        float w = Wz[(size_t)k * N + c];
        sg += g[(size_t)z * K + k] * w;
        bw += b[(size_t)z * K + k] * w;
    }
    SGW[(size_t)z * N + c] = sg;
    BW[(size_t)z * N + c] = bw + bias[(size_t)z * N + c];
}

// EQ[v] = (emb[v]*scale) @ Wqkv0 + bqkv0 ; PEQ[t] = peR[t] @ Wqkv0
__global__ __launch_bounds__(256) void k_eqpeq(
    const float* __restrict__ emb, const float* __restrict__ peR,
    const float* __restrict__ W0, const float* __restrict__ b0,
    float* __restrict__ EQ, float* __restrict__ PEQ)
{
    __shared__ float x[DD];
    int row = blockIdx.x, tid = threadIdx.x;
    bool isE = row < VV;
    for (int k = tid; k < DD; k += 256)
        x[k] = isE ? emb[(size_t)row * DD + k] * EMB_SCALE : peR[(row - VV) * DD + k];
    __syncthreads();
    for (int c = tid; c < 3 * DD; c += 256) {
        float a = isE ? b0[c] : 0.f;
        for (int k = 0; k < DD; ++k) a += x[k] * W0[(size_t)k * (3 * DD) + c];
        if (isE) EQ[(size_t)row * (3 * DD) + c] = a;
        else     PEQ[(size_t)(row - VV) * (3 * DD) + c] = a;
    }
}

// qkv0 / x0 for t=0 (token = SOS)
__global__ __launch_bounds__(256) void k_seed(
    const float* __restrict__ EQ, const float* __restrict__ PEQ,
    const float* __restrict__ emb, const float* __restrict__ peR,
    float* __restrict__ qbuf, float* __restrict__ Ksa, float* __restrict__ Vsa,
    float* __restrict__ x0buf)
{
    int b = blockIdx.x, tid = threadIdx.x;
    for (int c = tid; c < 3 * DD; c += 256) {
        float v = EQ[(size_t)SOS_T * (3 * DD) + c] + PEQ[c];
        if (c < DD)            qbuf[b * DD + c] = v;
        else if (c < 2 * DD)   Ksa[((size_t)b * LLEN) * DD + (c - DD)] = v;
        else                   Vsa[((size_t)b * LLEN) * DD + (c - 2 * DD)] = v;
    }
    for (int c = tid; c < DD; c += 256)
        x0buf[b * DD + c] = emb[(size_t)SOS_T * DD + c] * EMB_SCALE + peR[c];
}

// memory @ ca_kv_w (hoisted, fp32)
__global__ __launch_bounds__(256) void memkv_kernel(
    const float* __restrict__ mem, const float* __restrict__ Wkv, const float* __restrict__ bkv,
    float* __restrict__ Kmem, float* __restrict__ Vmem)
{
    int l = blockIdx.z;
    const float* Wl = Wkv + (size_t)l * DD * (2 * DD);
    const float* bl = bkv + l * (2 * DD);
    int brow = blockIdx.y * 64, bcol = blockIdx.x * 64;
    __shared__ float As[64][20];
    __shared__ float Bs[16][68];
    int tid = threadIdx.x;
    int ty = tid / 16, tx = tid % 16;
    float acc[4][4] = {};
    for (int k0 = 0; k0 < DD; k0 += 16) {
        {
            int r = tid >> 2, kk = (tid & 3) * 4;
            const float4 av = *(const float4*)(mem + (size_t)(brow + r) * DD + k0 + kk);
            As[r][kk] = av.x; As[r][kk + 1] = av.y; As[r][kk + 2] = av.z; As[r][kk + 3] = av.w;
        }
        {
            int kb = tid >> 4, j = (tid & 15) * 4;
            const float4 bv = *(const float4*)(Wl + (size_t)(k0 + kb) * (2 * DD) + bcol + j);
            Bs[kb][j] = bv.x; Bs[kb][j + 1] = bv.y; Bs[kb][j + 2] = bv.z; Bs[kb][j + 3] = bv.w;
        }
        __syncthreads();
        #pragma unroll
        for (int kk2 = 0; kk2 < 16; kk2++) {
            float a0 = As[ty * 4 + 0][kk2], a1 = As[ty * 4 + 1][kk2];
            float a2 = As[ty * 4 + 2][kk2], a3 = As[ty * 4 + 3][kk2];
            float b0 = Bs[kk2][tx * 4 + 0], b1 = Bs[kk2][tx * 4 + 1];
            float b2 = Bs[kk2][tx * 4 + 2], b3 = Bs[kk2][tx * 4 + 3];
            acc[0][0] += a0 * b0; acc[0][1] += a0 * b1; acc[0][2] += a0 * b2; acc[0][3] += a0 * b3;
            acc[1][0] += a1 * b0; acc[1][1] += a1 * b1; acc[1][2] += a1 * b2; acc[1][3] += a1 * b3;
            acc[2][0] += a2 * b0; acc[2][1] += a2 * b1; acc[2][2] += a2 * b2; acc[2][3] += a2 * b3;
            acc[3][0] += a3 * b0; acc[3][1] += a3 * b1; acc[3][2] += a3 * b2; acc[3][3] += a3 * b3;
        }
        __syncthreads();
    }
    for (int i = 0; i < 4; i++)
        for (int j = 0; j < 4; j++) {
            int row = brow + ty * 4 + i, colg = bcol + tx * 4 + j;
            float v = acc[i][j] + bl[colg];
            if (colg < DD) Kmem[((size_t)l * (BB * SMEMN) + row) * DD + colg] = v;
            else           Vmem[((size_t)l * (BB * SMEMN) + row) * DD + (colg - DD)] = v;
        }
}

// ---------------------------------------------------------- one-hop barrier
__device__ __forceinline__ void gbar(int* flags, int gen, int bid, int tid) {
    asm volatile("s_waitcnt vmcnt(0)" ::: "memory");
    __syncthreads();
    if (tid == 0) icstore(flags + bid, gen);
    int spins = 0;
    while (icload(flags + tid) < gen) {
        __builtin_amdgcn_s_sleep(4);
        if (++spins > (1 << 14)) break;   // escape hatch
    }
    __syncthreads();
}

// ------------------------------------------- stage 8x512 + optional row stats
__device__ __forceinline__ void stage_stats(
    float* dst, int pitch, const float* src, float* mO, float* rO, int tid, int dostats)
{
    int r = tid >> 5, lane = tid & 31;
    const float* s = src + r * DD + lane * 16;
    float* d = dst + r * pitch + lane * 16;
    float sum = 0.f, sq = 0.f;
    #pragma unroll
    for (int j = 0; j < 8; ++j) {
        float2 v = cload2(s + 2 * j);
        d[2 * j] = v.x; d[2 * j + 1] = v.y;
        sum += v.x + v.y; sq += v.x * v.x + v.y * v.y;
    }
    if (dostats) {
        for (int off = 16; off; off >>= 1) {
            sum += __shfl_down(sum, off, 32); sq += __shfl_down(sq, off, 32);
        }
        if (lane == 0) {
            float m = sum * (1.f / 512.f);
            mO[r] = m; rO[r] = rsqrtf(sq * (1.f / 512.f) - m * m + 1e-5f);
        }
    }
}

__device__ __forceinline__ void stage_hb(float* xs_, const float* hb, int ch, int tid) {
    int r = tid >> 5, lane = tid & 31;
    const float* s = hb + r * DFFN + ch * 1024 + lane * 32;
    float* d = xs_ + r * XP + lane * 32;
    #pragma unroll
    for (int j = 0; j < 16; ++j) {
        float2 v = cload2(s + 2 * j);
        d[2 * j] = v.x; d[2 * j + 1] = v.y;
    }
}

// ------------------------------------------------------------ GEMV pieces
template <int NCOL, int KTOT>
__device__ __forceinline__ void gemv_accum(
    const __half* wcol0, int ldw, int wkoff, const float* xsL, float acc[8], int tid)
{
    constexpr int NKS = 256 / NCOL;
    const int c = tid / NKS, ks = tid % NKS;
    const __half* w = wcol0 + (size_t)c * ldw + wkoff;
    #pragma unroll
    for (int j = 0; j < KTOT / (NKS * 4); ++j) {
        int k = j * (NKS * 4) + ks * 4;
        const __half2* w2 = (const __half2*)(w + k);
        float2 f0 = __half22float2(w2[0]);
        float2 f1 = __half22float2(w2[1]);
        #pragma unroll
        for (int r = 0; r < 8; ++r) {
            const float4 xv = *(const float4*)(xsL + r * XP + k);
            acc[r] += xv.x * f0.x + xv.y * f0.y + xv.z * f1.x + xv.w * f1.y;
        }
    }
}

template <int INLN, int RESMODE, int RELU, int ROUTE>
__device__ __forceinline__ void emit_one(
    int out_i, float v, int gcol0,
    const float* SGW, const float* BWp,
    const float* mS_, const float* rS_,
    const float* rsL, const float* rmS_, const float* rrS_,
    const float* resg, const float* resb,
    float* out, int outN, float* qb, float* ksa, float* vsa)
{
    int c2 = out_i >> 3, r = out_i & 7;
    int g = gcol0 + c2;
    if (INLN) v = rS_[r] * (v - mS_[r] * SGW[g]);
    v += BWp[g];
    if (RELU) v = fmaxf(v, 0.f);
    if (RESMODE == 1) v += rsL[r * RP + g];
    if (RESMODE == 2) {
        float rv = rsL[r * RP + g];
        v += (rv - rmS_[r]) * rrS_[r] * resg[g] + resb[g];
    }
    if (ROUTE) {
        if (g < DD)            cstore(qb + r * DD + g, v);
        else if (g < 2 * DD)   cstore(ksa + (size_t)r * (LLEN * DD) + (g - DD), v);
        else                   cstore(vsa + (size_t)r * (LLEN * DD) + (g - 2 * DD), v);
    } else {
        cstore(out + (size_t)r * outN + g, v);
    }
}

template <int NCOL, int INLN, int RESMODE, int RELU, int ROUTE>
__device__ __forceinline__ void gemv_finish(
    float acc[8], float* part, int tid, int gcol0,
    const float* SGW, const float* BWp,
    const float* mS_, const float* rS_,
    const float* rsL, const float* rmS_, const float* rrS_,
    const float* resg, const float* resb,
    float* out, int outN, float* qb, float* ksa, float* vsa)
{
    constexpr int NKS = 256 / NCOL, PP = NKS + 1;
    const int c = tid / NKS, ks = tid % NKS;
    #pragma unroll
    for (int r = 0; r < 8; ++r) part[(c * 8 + r) * PP + ks] = acc[r];
    __syncthreads();
    if (NCOL == 2) {
        int out_i = tid >> 4, t16 = tid & 15;
        float v = 0.f;
        #pragma unroll
        for (int j = 0; j < 8; ++j) v += part[out_i * PP + t16 + 16 * j];
        for (int off = 8; off; off >>= 1) v += __shfl_down(v, off, 16);
        if (t16 == 0)
            emit_one<INLN, RESMODE, RELU, ROUTE>(out_i, v, gcol0, SGW, BWp, mS_, rS_,
                                                 rsL, rmS_, rrS_, resg, resb, out, outN, qb, ksa, vsa);
    } else {  // NCOL == 8, NKS = 32
        int out_i = tid >> 2, t4 = tid & 3;
        float v = 0.f;
        #pragma unroll
        for (int j = 0; j < 8; ++j) v += part[out_i * PP + t4 + 4 * j];
        v += __shfl_down(v, 2, 4); v += __shfl_down(v, 1, 4);
        if (t4 == 0)
            emit_one<INLN, RESMODE, RELU, ROUTE>(out_i, v, gcol0, SGW, BWp, mS_, rS_,
                                                 rsL, rmS_, rrS_, resg, resb, out, outN, qb, ksa, vsa);
    }
    __syncthreads();
}

// ---------------------------------------------------------------- megakernel
struct MegaParams {
    const float *emb;
    const float *sa_out_b, *ca_out_b, *ffn_b2;
    const float *ln1_g, *ln1_b, *ln2_g, *ln2_b, *ln3_g, *ln3_b;
    const __half *qkvGW16, *saout16, *caq16, *caout16, *ffn116, *ffn216, *clfGW16;
    const float *qkvSGW, *qkvBW, *caqSGW, *caqBW, *ffn1SGW, *ffn1BW, *clfSGW, *clfBW;
    const float *EQ, *PEQ, *peR;
    int *tokens, *flags;
    float *Kmem, *Vmem, *Ksa, *Vsa;
    float *qbuf, *attnb, *y1, *qca, *cat, *y2, *hb, *y3, *x0buf;
    float *out_logits, *out_sampled;
};

__device__ __forceinline__ void cp16(__half* dst, const __half* src, int halfs, int tid) {
    const int4* s = (const int4*)src;
    int4* d = (int4*)dst;
    int n = halfs >> 3;
    for (int i = tid; i < n; i += 256) d[i] = s[i];
}

__global__ __launch_bounds__(256, 1) void mega_kernel(MegaParams p) {
    __shared__ __align__(16) __half wlds[WTOT];   // 85.0 KB
    __shared__ float xs[BB * XP];                  // 32.9 KB
    __shared__ float rs[BB * RP];                  // 16.6 KB
    __shared__ float part[2112];                   // 8.4 KB
    __shared__ float mS[8], rS[8], rmS[8], rrS[8], clfred[12];
    __shared__ int   tokLDS;
    __shared__ float argv[2];
    __shared__ int   argi[2];
    const int tid = threadIdx.x, bid = blockIdx.x;
    int gen = 0;

    // ---- one-time LDS weight fill ----
    if (bid < 192) {
        cp16(wlds + OFF_QKV,        p.qkvGW16 + ((size_t)0 * 1536 + bid * 8) * WLD, 8 * WLD, tid);
        cp16(wlds + OFF_QKV + 4160, p.qkvGW16 + ((size_t)1 * 1536 + bid * 8) * WLD, 8 * WLD, tid);
    }
    for (int l = 0; l < NLAYER; ++l) {
        cp16(wlds + OFF_SAOUT + l * 1040, p.saout16 + ((size_t)l * 512 + bid * 2) * WLD, 2 * WLD, tid);
        cp16(wlds + OFF_CAQ   + l * 1040, p.caq16   + ((size_t)l * 512 + bid * 2) * WLD, 2 * WLD, tid);
        cp16(wlds + OFF_CAOUT + l * 1040, p.caout16 + ((size_t)l * 512 + bid * 2) * WLD, 2 * WLD, tid);
        cp16(wlds + OFF_FFN1  + l * 4160, p.ffn116  + ((size_t)l * 2048 + bid * 8) * WLD, 8 * WLD, tid);
        cp16(wlds + OFF_FFN2  + l * 4112, p.ffn216  + ((size_t)l * 512 + bid * 2) * WLD2, 2 * WLD2, tid);
    }
    __syncthreads();

    for (int t = 0; t < LLEN; ++t) {
        for (int l = 0; l < NLAYER; ++l) {
            // ---- P1 qkv (l>=1): LN3-folded GEMV, 192 blocks x 8 cols ----
            if (l > 0) {
                if (bid < 192) {
                    stage_stats(xs, XP, p.y3, mS, rS, tid, 1);
                    __syncthreads();
                    float acc[8] = {};
                    gemv_accum<8, 512>(wlds + OFF_QKV + (l - 1) * 4160, WLD, 0, xs, acc, tid);
                    gemv_finish<8, 1, 0, 0, 1>(acc, part, tid, bid * 8,
                        p.qkvSGW + (l - 1) * 1536, p.qkvBW + (l - 1) * 1536, mS, rS,
                        nullptr, nullptr, nullptr, nullptr, nullptr,
                        nullptr, 0, p.qbuf,
                        p.Ksa + ((size_t)(l * 8) * LLEN + t) * DD,
                        p.Vsa + ((size_t)(l * 8) * LLEN + t) * DD);
                }
                gbar(p.flags, ++gen, bid, tid);
            }

            // ---- P2 self-attention (64 blocks) ----
            if (bid < 64) {
                const int b = bid >> 3, h = bid & 7;
                float* qsh = part;        // 64
                float* sc  = part + 64;   // 32
                float* po  = part + 128;  // 256
                if (tid < 64) qsh[tid] = cload(p.qbuf + b * DD + h * HDIM + tid);
                __syncthreads();
                const int w = tid >> 6, lane = tid & 63;
                const float* Kb = p.Ksa + ((size_t)(l * 8 + b)) * (LLEN * DD) + h * HDIM;
                for (int j = w; j <= t; j += 4) {
                    const float* kp = Kb + (size_t)j * DD + lane;
                    float kv = (j == t) ? cload(kp) : *kp;   // row t is fresh this step
                    float v = qsh[lane] * kv;
                    for (int off = 32; off; off >>= 1) v += __shfl_down(v, off);
                    if (lane == 0) sc[j] = v * 0.125f;
                }
                __syncthreads();
                if (tid < 64) {
                    float s = (tid <= t) ? sc[tid] : -1e30f;
                    float mx = s;
                    for (int off = 32; off; off >>= 1) mx = fmaxf(mx, __shfl_xor(mx, off));
                    float pe = (tid <= t) ? expf(s - mx) : 0.f;
                    float sum = pe;
                    for (int off = 32; off; off >>= 1) sum += __shfl_xor(sum, off);
                    if (tid <= t) sc[tid] = pe / sum;
                }
                __syncthreads();
                {
                    const float* Vb = p.Vsa + ((size_t)(l * 8 + b)) * (LLEN * DD) + h * HDIM;
                    float o = 0.f;
                    for (int j = w; j <= t; j += 4) {
                        const float* vp = Vb + (size_t)j * DD + lane;
                        float vv = (j == t) ? cload(vp) : *vp;
                        o += sc[j] * vv;
                    }
                    po[w * 64 + lane] = o;
                }
                __syncthreads();
                if (tid < 64)
                    cstore(p.attnb + b * DD + h * HDIM + tid,
                           po[tid] + po[64 + tid] + po[128 + tid] + po[192 + tid]);
            }
            gbar(p.flags, ++gen, bid, tid);

            // ---- P3 saout + residual (raw embed l=0 | LN3-fold l>=1) ----
            {
                stage_stats(xs, XP, p.attnb, mS, rS, tid, 0);
                if (l == 0) stage_stats(rs, RP, p.x0buf, rmS, rrS, tid, 0);
                else        stage_stats(rs, RP, p.y3,    rmS, rrS, tid, 1);
                __syncthreads();
                float acc[8] = {};
                gemv_accum<2, 512>(wlds + OFF_SAOUT + l * 1040, WLD, 0, xs, acc, tid);
                if (l == 0)
                    gemv_finish<2, 0, 1, 0, 0>(acc, part, tid, bid * 2,
                        nullptr, p.sa_out_b + l * DD, nullptr, nullptr,
                        rs, nullptr, nullptr, nullptr, nullptr,
                        p.y1, DD, nullptr, nullptr, nullptr);
                else
                    gemv_finish<2, 0, 2, 0, 0>(acc, part, tid, bid * 2,
                        nullptr, p.sa_out_b + l * DD, nullptr, nullptr,
                        rs, rmS, rrS, p.ln3_g + (l - 1) * DD, p.ln3_b + (l - 1) * DD,
                        p.y1, DD, nullptr, nullptr, nullptr);
            }
            gbar(p.flags, ++gen, bid, tid);

            // ---- P4 ca_q: LN1-folded GEMV ----
            {
                stage_stats(xs, XP, p.y1, mS, rS, tid, 1);
                __syncthreads();
                float acc[8] = {};
                gemv_accum<2, 512>(wlds + OFF_CAQ + l * 1040, WLD, 0, xs, acc, tid);
                gemv_finish<2, 1, 0, 0, 0>(acc, part, tid, bid * 2,
                    p.caqSGW + l * DD, p.caqBW + l * DD, mS, rS,
                    nullptr, nullptr, nullptr, nullptr, nullptr,
                    p.qca, DD, nullptr, nullptr, nullptr);
            }
            gbar(p.flags, ++gen, bid, tid);

            // ---- P5 cross-attention (64 blocks) ----
            if (bid < 64) {
                const int b = bid >> 3, h = bid & 7;
                float* qsh = part;         // 64
                float* sc  = part + 64;    // 128
                float* po  = part + 192;   // 128
                if (tid < 64) qsh[tid] = cload(p.qca + b * DD + h * HDIM + tid);
                __syncthreads();
                if (tid < 128) {
                    const float* kp = p.Kmem + (((size_t)(l * 8 + b)) * SMEMN + tid) * DD + h * HDIM;
                    float s = 0.f;
                    #pragma unroll 8
                    for (int d = 0; d < HDIM; ++d) s += qsh[d] * kp[d];
                    sc[tid] = s * 0.125f;
                }
                __syncthreads();
                if (tid < 64) {
                    float s0 = sc[tid], s1 = sc[tid + 64];
                    float mx = fmaxf(s0, s1);
                    for (int off = 32; off; off >>= 1) mx = fmaxf(mx, __shfl_xor(mx, off));
                    float e0 = expf(s0 - mx), e1 = expf(s1 - mx);
                    float sum = e0 + e1;
                    for (int off = 32; off; off >>= 1) sum += __shfl_xor(sum, off);
                    sc[tid] = e0 / sum; sc[tid + 64] = e1 / sum;
                }
                __syncthreads();
                if (tid < 128) {
                    int d = tid & 63, half = tid >> 6;
                    const float* Vb = p.Vmem + (((size_t)(l * 8 + b)) * SMEMN + half * 64) * DD + h * HDIM + d;
                    float o = 0.f;
                    for (int j = 0; j < 64; ++j) o += sc[half * 64 + j] * Vb[(size_t)j * DD];
                    po[half * 64 + d] = o;
                }
                __syncthreads();
                if (tid < 64)
                    cstore(p.cat + b * DD + h * HDIM + tid, po[tid] + po[64 + tid]);
            }
            gbar(p.flags, ++gen, bid, tid);

            // ---- P6 caout + residual LN1(y1)-fold ----
            {
                stage_stats(xs, XP, p.cat, mS, rS, tid, 0);
                stage_stats(rs, RP, p.y1, rmS, rrS, tid, 1);
                __syncthreads();
                float acc[8] = {};
                gemv_accum<2, 512>(wlds + OFF_CAOUT + l * 1040, WLD, 0, xs, acc, tid);
                gemv_finish<2, 0, 2, 0, 0>(acc, part, tid, bid * 2,
                    nullptr, p.ca_out_b + l * DD, nullptr, nullptr,
                    rs, rmS, rrS, p.ln1_g + l * DD, p.ln1_b + l * DD,
                    p.y2, DD, nullptr, nullptr, nullptr);
            }
            gbar(p.flags, ++gen, bid, tid);

            // ---- P7 ffn1: LN2-folded GEMV + relu ----
            {
                stage_stats(xs, XP, p.y2, mS, rS, tid, 1);
                __syncthreads();
                float acc[8] = {};
                gemv_accum<8, 512>(wlds + OFF_FFN1 + l * 4160, WLD, 0, xs, acc, tid);
                gemv_finish<8, 1, 0, 1, 0>(acc, part, tid, bid * 8,
                    p.ffn1SGW + l * DFFN, p.ffn1BW + l * DFFN, mS, rS,
                    nullptr, nullptr, nullptr, nullptr, nullptr,
                    p.hb, DFFN, nullptr, nullptr, nullptr);
            }
            gbar(p.flags, ++gen, bid, tid);

            // ---- P8 ffn2 (K=2048 in 2 chunks) + residual LN2(y2)-fold ----
            {
                stage_stats(rs, RP, p.y2, rmS, rrS, tid, 1);
                stage_hb(xs, p.hb, 0, tid);
                __syncthreads();
                float acc[8] = {};
                gemv_accum<2, 1024>(wlds + OFF_FFN2 + l * 4112, WLD2, 0, xs, acc, tid);
                __syncthreads();
                stage_hb(xs, p.hb, 1, tid);
                __syncthreads();
                gemv_accum<2, 1024>(wlds + OFF_FFN2 + l * 4112, WLD2, 1024, xs, acc, tid);
                gemv_finish<2, 0, 2, 0, 0>(acc, part, tid, bid * 2,
                    nullptr, p.ffn_b2 + l * DD, nullptr, nullptr,
                    rs, rmS, rrS, p.ln2_g + l * DD, p.ln2_b + l * DD,
                    p.y3, DD, nullptr, nullptr, nullptr);
            }
            gbar(p.flags, ++gen, bid, tid);
        }

        // ---- CLF: LN3-folded logits + argmax + next-step qkv0/x0 lookup ----
        if (bid < 8) {
            const int b = bid;
            // stage y3[b] into rs[0..512) + stats
            {
                float2 v = cload2(p.y3 + b * DD + tid * 2);
                rs[tid * 2] = v.x; rs[tid * 2 + 1] = v.y;
                float sum = v.x + v.y, sq = v.x * v.x + v.y * v.y;
                for (int off = 32; off; off >>= 1) {
                    sum += __shfl_down(sum, off); sq += __shfl_down(sq, off);
                }
                if ((tid & 63) == 0) { clfred[tid >> 6] = sum; clfred[4 + (tid >> 6)] = sq; }
                __syncthreads();
                if (tid == 0) {
                    float s = clfred[0] + clfred[1] + clfred[2] + clfred[3];
                    float q = clfred[4] + clfred[5] + clfred[6] + clfred[7];
                    float m = s * (1.f / 512.f);
                    clfred[8] = m; clfred[9] = rsqrtf(q * (1.f / 512.f) - m * m + 1e-5f);
                }
                __syncthreads();
            }
            {
                int cl = tid & 127, kh = tid >> 7;
                const __half2* w2 = (const __half2*)(p.clfGW16 + (size_t)cl * 512 + kh * 256);
                const float* xh = rs + kh * 256;
                float lg = 0.f;
                #pragma unroll 8
                for (int k2 = 0; k2 < 128; ++k2) {
                    float2 f = __half22float2(w2[k2]);
                    lg += xh[2 * k2] * f.x + xh[2 * k2 + 1] * f.y;
                }
                part[tid] = lg;
            }
            __syncthreads();
            if (tid < 128) {
                float m = clfred[8], ri = clfred[9];
                float lg = ri * ((part[tid] + part[128 + tid]) - m * p.clfSGW[tid]) + p.clfBW[tid];
                p.out_logits[((size_t)b * LLEN + t) * VV + tid] = lg;
                float bv = lg; int bi = tid;
                for (int off = 32; off; off >>= 1) {
                    float ov = __shfl_xor(bv, off); int oi = __shfl_xor(bi, off);
                    if (ov > bv || (ov == bv && oi < bi)) { bv = ov; bi = oi; }
                }
                if ((tid & 63) == 0) { argv[tid >> 6] = bv; argi[tid >> 6] = bi; }
            }
            __syncthreads();
            if (tid == 0) {
                int best = (argv[1] > argv[0] || (argv[1] == argv[0] && argi[1] < argi[0]))
                               ? argi[1] : argi[0];
                icstore(p.tokens + b * (LLEN + 1) + t + 1, best);
                tokLDS = best;
            }
            __syncthreads();
            if (t < LLEN - 1) {
                int tok = tokLDS, tn = t + 1;
                for (int c = tid; c < 3 * DD; c += 256) {
                    float v = p.EQ[(size_t)tok * (3 * DD) + c] + p.PEQ[(size_t)tn * (3 * DD) + c];
                    if (c < DD)          cstore(p.qbuf + b * DD + c, v);
                    else if (c < 2 * DD) cstore(p.Ksa + ((size_t)b * LLEN + tn) * DD + (c - DD), v);
                    else                 cstore(p.Vsa + ((size_t)b * LLEN + tn) * DD + (c - 2 * DD), v);
                }
                for (int c = tid; c < DD; c += 256)
                    cstore(p.x0buf + b * DD + c,
                           p.emb[(size_t)tok * DD + c] * EMB_SCALE + p.peR[(size_t)tn * DD + c]);
            }
        }
        gbar(p.flags, ++gen, bid, tid);
    }

    // ---- finalize sampled ----
    if (bid == 0 && tid < BB) {
        int b = tid;
        int toks[LLEN + 1];
        for (int j = 0; j <= LLEN; j++) toks[j] = icload(p.tokens + b * (LLEN + 1) + j);
        int eos = 0;
        for (int j = 1; j <= LLEN; j++)
            if (toks[j] == EOS_T) { eos = j; break; }
        for (int j = 0; j <= LLEN; j++) {
            int v = toks[j];
            if (eos != 0 && j > eos + 1) v = PAD_T;
            p.out_sampled[b * (LLEN + 1) + j] = (float)v;
        }
    }
}

// --------------------------------------------------------------------- host
extern "C" void kernel_launch(void* const* d_in, const int* in_sizes, int n_in,
                              void* d_out, int out_size, void* d_ws, size_t ws_size,
                              hipStream_t stream) {
    const float* memory   = (const float*)d_in[0];
    const float* emb      = (const float*)d_in[1];
    const float* sa_qkv_w = (const float*)d_in[2];
    const float* sa_qkv_b = (const float*)d_in[3];
    const float* sa_out_w = (const float*)d_in[4];
    const float* sa_out_b = (const float*)d_in[5];
    const float* ca_q_w   = (const float*)d_in[6];
    const float* ca_q_b   = (const float*)d_in[7];
    const float* ca_kv_w  = (const float*)d_in[8];
    const float* ca_kv_b  = (const float*)d_in[9];
    const float* ca_out_w = (const float*)d_in[10];
    const float* ca_out_b = (const float*)d_in[11];
    const float* ln1_g    = (const float*)d_in[12];
    const float* ln1_b    = (const float*)d_in[13];
    const float* ln2_g    = (const float*)d_in[14];
    const float* ln2_b    = (const float*)d_in[15];
    const float* ln3_g    = (const float*)d_in[16];
    const float* ln3_b    = (const float*)d_in[17];
    const float* ffn_w1   = (const float*)d_in[18];
    const float* ffn_b1   = (const float*)d_in[19];
    const float* ffn_w2   = (const float*)d_in[20];
    const float* ffn_b2   = (const float*)d_in[21];
    const float* clf_w    = (const float*)d_in[22];
    const float* clf_b    = (const float*)d_in[23];

    float* f   = (float*)d_ws;
    int*   wsI = (int*)d_ws;
    int* flags  = wsI;                 // 256 ints
    int* tokens = wsI + 256;           // 264 ints (to float offset 1024)
    float* peR  = f + 1024;            // 32*512
    float* Kmem = peR + LLEN * DD;                              // 3*8*128*512
    float* Vmem = Kmem + (size_t)NLAYER * BB * SMEMN * DD;
    float* Ksa  = Vmem + (size_t)NLAYER * BB * SMEMN * DD;      // 3*8*32*512
    float* Vsa  = Ksa  + (size_t)NLAYER * BB * LLEN * DD;
    float* qbuf = Vsa  + (size_t)NLAYER * BB * LLEN * DD;
    float* attnb= qbuf + BB * DD;
    float* y1   = attnb+ BB * DD;
    float* qca  = y1   + BB * DD;
    float* cat  = qca  + BB * DD;
    float* y2   = cat  + BB * DD;
    float* hb   = y2   + BB * DD;
    float* y3   = hb   + BB * DFFN;
    float* x0buf= y3   + BB * DD;
    float* EQ   = x0buf+ BB * DD;                               // 128*1536
    float* PEQ  = EQ   + (size_t)VV * 3 * DD;                   // 32*1536
    float* qkvSGW = PEQ + (size_t)LLEN * 3 * DD;                // 2*1536
    float* qkvBW  = qkvSGW + 2 * 1536;
    float* caqSGW = qkvBW  + 2 * 1536;                          // 3*512
    float* caqBW  = caqSGW + 3 * 512;
    float* ffn1SGW= caqBW  + 3 * 512;                           // 3*2048
    float* ffn1BW = ffn1SGW+ 3 * 2048;
    float* clfSGW = ffn1BW + 3 * 2048;                          // 128
    float* clfBW  = clfSGW + 128;
    __half* qkvGW16 = (__half*)(clfBW + 128);                   // 2*1536*520
    __half* saout16 = qkvGW16 + (size_t)2 * 1536 * WLD;         // 3*512*520
    __half* caq16   = saout16 + (size_t)3 * 512 * WLD;
    __half* caout16 = caq16   + (size_t)3 * 512 * WLD;
    __half* ffn116  = caout16 + (size_t)3 * 512 * WLD;          // 3*2048*520
    __half* ffn216  = ffn116  + (size_t)3 * 2048 * WLD;         // 3*512*2056
    __half* clfGW16 = ffn216  + (size_t)3 * 512 * WLD2;         // 128*512

    float* out_logits  = (float*)d_out;
    float* out_sampled = out_logits + (size_t)BB * LLEN * VV;

    hipMemsetAsync(d_ws, 0, 4096, stream);   // flags + tokens region
    k_init<<<1, 512, 0, stream>>>(tokens, peR);

    // folded / transposed fp16 weights
    t16pad<<<dim3(16, 48, 2), 256, 0, stream>>>(sa_qkv_w + (size_t)512 * 1536, ln3_g, qkvGW16, 512, 1536, WLD);
    t16pad<<<dim3(16, 16, 3), 256, 0, stream>>>(sa_out_w, nullptr, saout16, 512, 512, WLD);
    t16pad<<<dim3(16, 16, 3), 256, 0, stream>>>(ca_q_w,   ln1_g,   caq16,   512, 512, WLD);
    t16pad<<<dim3(16, 16, 3), 256, 0, stream>>>(ca_out_w, nullptr, caout16, 512, 512, WLD);
    t16pad<<<dim3(16, 64, 3), 256, 0, stream>>>(ffn_w1,   ln2_g,   ffn116,  512, 2048, WLD);
    t16pad<<<dim3(64, 16, 3), 256, 0, stream>>>(ffn_w2,   nullptr, ffn216,  2048, 512, WLD2);
    t16pad<<<dim3(16, 4, 1),  256, 0, stream>>>(clf_w,    ln3_g + 2 * 512, clfGW16, 512, 128, 512);

    // fp32 column vectors for LN folding
    k_colvec<<<dim3(6, 2), 256, 0, stream>>>(sa_qkv_w + (size_t)512 * 1536, ln3_g, ln3_b,
                                             sa_qkv_b + 1536, qkvSGW, qkvBW, 512, 1536);
    k_colvec<<<dim3(2, 3), 256, 0, stream>>>(ca_q_w, ln1_g, ln1_b, ca_q_b, caqSGW, caqBW, 512, 512);
    k_colvec<<<dim3(8, 3), 256, 0, stream>>>(ffn_w1, ln2_g, ln2_b, ffn_b1, ffn1SGW, ffn1BW, 512, 2048);
    k_colvec<<<dim3(1, 1), 256, 0, stream>>>(clf_w, ln3_g + 1024, ln3_b + 1024, clf_b,
                                             clfSGW, clfBW, 512, 128);

    k_eqpeq<<<VV + LLEN, 256, 0, stream>>>(emb, peR, sa_qkv_w, sa_qkv_b, EQ, PEQ);
    memkv_kernel<<<dim3(16, 16, 3), 256, 0, stream>>>(memory, ca_kv_w, ca_kv_b, Kmem, Vmem);
    k_seed<<<8, 256, 0, stream>>>(EQ, PEQ, emb, peR, qbuf, Ksa, Vsa, x0buf);

    MegaParams p;
    p.emb = emb;
    p.sa_out_b = sa_out_b; p.ca_out_b = ca_out_b; p.ffn_b2 = ffn_b2;
    p.ln1_g = ln1_g; p.ln1_b = ln1_b;
    p.ln2_g = ln2_g; p.ln2_b = ln2_b;
    p.ln3_g = ln3_g; p.ln3_b = ln3_b;
    p.qkvGW16 = qkvGW16; p.saout16 = saout16; p.caq16 = caq16; p.caout16 = caout16;
    p.ffn116 = ffn116; p.ffn216 = ffn216; p.clfGW16 = clfGW16;
    p.qkvSGW = qkvSGW; p.qkvBW = qkvBW; p.caqSGW = caqSGW; p.caqBW = caqBW;
    p.ffn1SGW = ffn1SGW; p.ffn1BW = ffn1BW; p.clfSGW = clfSGW; p.clfBW = clfBW;
    p.EQ = EQ; p.PEQ = PEQ; p.peR = peR;
    p.tokens = tokens; p.flags = flags;
    p.Kmem = Kmem; p.Vmem = Vmem; p.Ksa = Ksa; p.Vsa = Vsa;
    p.qbuf = qbuf; p.attnb = attnb; p.y1 = y1; p.qca = qca;
    p.cat = cat; p.y2 = y2; p.hb = hb; p.y3 = y3; p.x0buf = x0buf;
    p.out_logits = out_logits; p.out_sampled = out_sampled;

    mega_kernel<<<NB, 256, 0, stream>>>(p);
}